// Round 1
// baseline (1858.945 us; speedup 1.0000x reference)
//
#include <hip/hip_runtime.h>
#include <hip/hip_bf16.h>
#include <math.h>

// Problem constants (from reference setup_inputs)
#define F_IN 512
#define HID  16
#define C_OUT 40

// ---------------------------------------------------------------------------
// K0: init — deg = 1.0 (self-loop weight), agg = 0
// ---------------------------------------------------------------------------
__global__ __launch_bounds__(256) void k_init(float* __restrict__ deg,
                                              float* __restrict__ agg,
                                              int N) {
    int t = blockIdx.x * 256 + threadIdx.x;
    int total = N * HID;
    if (t < total) agg[t] = 0.0f;
    if (t < N) deg[t] = 1.0f;
}

// ---------------------------------------------------------------------------
// K1: deg[c] += ew  over all edges
// ---------------------------------------------------------------------------
__global__ __launch_bounds__(256) void k_deg(const int* __restrict__ col,
                                             const float* __restrict__ ew,
                                             float* __restrict__ deg,
                                             int E) {
    int e = blockIdx.x * 256 + threadIdx.x;
    if (e < E) {
        unsafeAtomicAdd(&deg[col[e]], ew[e]);
    }
}

// ---------------------------------------------------------------------------
// K2: dinv = rsqrt(deg)   (deg >= 1 always)
// ---------------------------------------------------------------------------
__global__ __launch_bounds__(256) void k_dinv(float* __restrict__ deg, int N) {
    int t = blockIdx.x * 256 + threadIdx.x;
    if (t < N) deg[t] = rsqrtf(deg[t]);
}

// ---------------------------------------------------------------------------
// K3: h1 = x @ W1   ([N,512] @ [512,16])
// 256 threads/block = 16 nodes x 16 outputs. x tile + W1 staged in LDS.
// ---------------------------------------------------------------------------
#define XPAD 516  // row stride in floats (516 % 32 == 4 -> conflict-free, 16B aligned)
__global__ __launch_bounds__(256) void k_gemm1(const float* __restrict__ x,
                                               const float* __restrict__ W,
                                               float* __restrict__ h,
                                               int N) {
    __shared__ float xs[16 * XPAD];
    __shared__ float Ws[F_IN * HID];
    int tid = threadIdx.x;
    int n0 = blockIdx.x * 16;

    // stage W1 (512*16 = 8192 floats = 2048 float4)
    const float4* Wv = (const float4*)W;
    float4* Wsv = (float4*)Ws;
    for (int i = tid; i < 2048; i += 256) Wsv[i] = Wv[i];

    // stage 16 rows of x (each row 512 floats = 128 float4)
    for (int i = tid; i < 2048; i += 256) {
        int r = i >> 7;        // row within tile
        int kq = i & 127;      // float4 index within row
        if (n0 + r < N) {
            float4 v = ((const float4*)(x + (size_t)(n0 + r) * F_IN))[kq];
            ((float4*)(xs + r * XPAD))[kq] = v;
        }
    }
    __syncthreads();

    int j = tid & 15;
    int nl = tid >> 4;
    if (n0 + nl >= N) return;
    const float* xr = xs + nl * XPAD;
    const float* wc = Ws + j;
    float acc = 0.0f;
#pragma unroll 8
    for (int k = 0; k < F_IN; ++k) {
        acc += xr[k] * wc[k * HID];
    }
    h[(size_t)(n0 + nl) * HID + j] = acc;
}

// ---------------------------------------------------------------------------
// K4/K6: scatter — agg[col] += norm * src[row]  (16 dims, 4 threads/edge)
// ---------------------------------------------------------------------------
__global__ __launch_bounds__(256) void k_scatter(const float* __restrict__ src,
                                                 const int* __restrict__ row,
                                                 const int* __restrict__ col,
                                                 const float* __restrict__ ew,
                                                 const float* __restrict__ dinv,
                                                 float* __restrict__ agg,
                                                 int E) {
    int t = blockIdx.x * 256 + threadIdx.x;
    int e = t >> 2;
    if (e >= E) return;
    int q = t & 3;
    int r = row[e];
    int c = col[e];
    float nrm = dinv[r] * ew[e] * dinv[c];
    float4 v = ((const float4*)(src + (size_t)r * HID))[q];
    float* dst = agg + (size_t)c * HID + q * 4;
    unsafeAtomicAdd(dst + 0, v.x * nrm);
    unsafeAtomicAdd(dst + 1, v.y * nrm);
    unsafeAtomicAdd(dst + 2, v.z * nrm);
    unsafeAtomicAdd(dst + 3, v.w * nrm);
}

// ---------------------------------------------------------------------------
// K5: finalize layer 1 — a1 = relu(agg + dinv^2 * h1 + b1); agg := 0 (reuse)
// ---------------------------------------------------------------------------
__global__ __launch_bounds__(256) void k_fin1(float* __restrict__ agg,
                                              const float* __restrict__ h1,
                                              const float* __restrict__ dinv,
                                              const float* __restrict__ b1,
                                              float* __restrict__ a1,
                                              int N) {
    int t = blockIdx.x * 256 + threadIdx.x;
    if (t >= N * HID) return;
    int n = t >> 4;
    int j = t & 15;
    float di = dinv[n];
    float v = agg[t] + di * di * h1[t] + b1[j];
    a1[t] = fmaxf(v, 0.0f);
    agg[t] = 0.0f;  // re-zero for layer 2 scatter
}

// ---------------------------------------------------------------------------
// K7: epilogue — g = agg + dinv^2*a1 ; logits = g@W2 + b2 ; log_softmax
// one wave per node; lanes 0..39 hold classes.
// ---------------------------------------------------------------------------
__global__ __launch_bounds__(256) void k_epilogue(const float* __restrict__ agg,
                                                  const float* __restrict__ a1,
                                                  const float* __restrict__ dinv,
                                                  const float* __restrict__ W2,
                                                  const float* __restrict__ b2,
                                                  float* __restrict__ out,
                                                  int N) {
    __shared__ float Ws[HID * C_OUT];
    __shared__ float bs[C_OUT];
    int tid = threadIdx.x;
    for (int i = tid; i < HID * C_OUT; i += 256) Ws[i] = W2[i];
    if (tid < C_OUT) bs[tid] = b2[tid];
    __syncthreads();

    int lane = tid & 63;
    int w = tid >> 6;
    int n = blockIdx.x * 4 + w;
    if (n >= N) return;

    float di = dinv[n];
    float di2 = di * di;
    float logit = -INFINITY;
    if (lane < C_OUT) {
        float acc = bs[lane];
        const float* ar = agg + (size_t)n * HID;
        const float* hr = a1 + (size_t)n * HID;
#pragma unroll
        for (int j = 0; j < HID; ++j) {
            float g = ar[j] + di2 * hr[j];
            acc += g * Ws[j * C_OUT + lane];
        }
        logit = acc;
    }
    // max over 40 valid lanes (inactive = -inf)
    float m = logit;
#pragma unroll
    for (int off = 32; off > 0; off >>= 1) m = fmaxf(m, __shfl_xor(m, off, 64));
    float ex = (lane < C_OUT) ? __expf(logit - m) : 0.0f;
    float s = ex;
#pragma unroll
    for (int off = 32; off > 0; off >>= 1) s += __shfl_xor(s, off, 64);
    if (lane < C_OUT) {
        out[(size_t)n * C_OUT + lane] = logit - m - __logf(s);
    }
}

// ---------------------------------------------------------------------------
extern "C" void kernel_launch(void* const* d_in, const int* in_sizes, int n_in,
                              void* d_out, int out_size, void* d_ws, size_t ws_size,
                              hipStream_t stream) {
    const float* x   = (const float*)d_in[0];
    const int*   ei  = (const int*)d_in[1];   // [2, E] int32 (jax default x64 off)
    const float* ew  = (const float*)d_in[2];
    const float* W1  = (const float*)d_in[3];
    const float* b1  = (const float*)d_in[4];
    const float* W2  = (const float*)d_in[5];
    const float* b2  = (const float*)d_in[6];
    float* out = (float*)d_out;

    const int N = in_sizes[0] / F_IN;     // 100000
    const int E = in_sizes[2];            // 3200000
    const int* row = ei;
    const int* col = ei + E;

    // workspace layout (floats)
    float* ws = (float*)d_ws;
    size_t npad = ((size_t)N + 127) & ~(size_t)127;
    float* deg = ws;                       // [N] -> becomes dinv in-place
    float* h1  = ws + npad;                // [N*16]
    float* a1  = h1 + (size_t)N * HID;     // [N*16]
    float* agg = a1 + (size_t)N * HID;     // [N*16]

    int gNH = (N * HID + 255) / 256;
    int gE  = (E + 255) / 256;
    int gN  = (N + 255) / 256;
    int gS  = (E * 4 + 255) / 256;

    // K0: init deg=1, agg=0
    k_init<<<gNH, 256, 0, stream>>>(deg, agg, N);
    // K1: accumulate weighted in-degree
    k_deg<<<gE, 256, 0, stream>>>(col, ew, deg, E);
    // K2: dinv = rsqrt(deg)
    k_dinv<<<gN, 256, 0, stream>>>(deg, N);
    // K3: h1 = x @ W1
    k_gemm1<<<(N + 15) / 16, 256, 0, stream>>>(x, W1, h1, N);
    // K4: scatter layer 1
    k_scatter<<<gS, 256, 0, stream>>>(h1, row, col, ew, deg, agg, E);
    // K5: finalize layer 1 (adds self-loop + bias, relu), re-zeros agg
    k_fin1<<<gNH, 256, 0, stream>>>(agg, h1, deg, b1, a1, N);
    // K6: scatter layer 2 (aggregate a1 in 16-dim space; (A a1) W2 == A (a1 W2))
    k_scatter<<<gS, 256, 0, stream>>>(a1, row, col, ew, deg, agg, E);
    // K7: epilogue — self-loop + @W2 + b2 + log_softmax
    k_epilogue<<<(N + 3) / 4, 256, 0, stream>>>(agg, a1, deg, W2, b2, out, N);
}

// Round 2
// 864.284 us; speedup vs baseline: 2.1508x; 2.1508x over previous
//
#include <hip/hip_runtime.h>
#include <hip/hip_bf16.h>
#include <math.h>

#define F_IN 512
#define HID  16
#define C_OUT 40

// ---------------------------------------------------------------------------
// K0: zero edge-count histogram
// ---------------------------------------------------------------------------
__global__ __launch_bounds__(256) void k_zero(int* __restrict__ cnt, int N) {
    int t = blockIdx.x * 256 + threadIdx.x;
    if (t < N) cnt[t] = 0;
}

// ---------------------------------------------------------------------------
// K1: histogram of destination nodes (int atomics, no return -> fast path)
// ---------------------------------------------------------------------------
__global__ __launch_bounds__(256) void k_hist(const int* __restrict__ col,
                                              int* __restrict__ cnt, int E) {
    int e = blockIdx.x * 256 + threadIdx.x;
    if (e < E) atomicAdd(&cnt[col[e]], 1);
}

// ---------------------------------------------------------------------------
// K2a: per-block exclusive scan of cnt -> offs (block-local), block sums
// ---------------------------------------------------------------------------
__global__ __launch_bounds__(256) void k_scan_block(const int* __restrict__ cnt,
                                                    int* __restrict__ offs,
                                                    int* __restrict__ bsum, int N) {
    __shared__ int s[256];
    int t = threadIdx.x;
    int n = blockIdx.x * 256 + t;
    int v = (n < N) ? cnt[n] : 0;
    s[t] = v;
    __syncthreads();
    for (int off = 1; off < 256; off <<= 1) {
        int x = (t >= off) ? s[t - off] : 0;
        __syncthreads();
        s[t] += x;
        __syncthreads();
    }
    if (n < N) offs[n] = s[t] - v;          // exclusive within block
    if (t == 255) bsum[blockIdx.x] = s[255];
}

// ---------------------------------------------------------------------------
// K2b: scan of block sums (single block, B <= 512) + set offs[N] = E
// ---------------------------------------------------------------------------
__global__ __launch_bounds__(512) void k_scan_top(int* __restrict__ bsum,
                                                  int* __restrict__ bbase,
                                                  int* __restrict__ offs,
                                                  int B, int N, int E) {
    __shared__ int s[512];
    int t = threadIdx.x;
    int v = (t < B) ? bsum[t] : 0;
    s[t] = v;
    __syncthreads();
    for (int off = 1; off < 512; off <<= 1) {
        int x = (t >= off) ? s[t - off] : 0;
        __syncthreads();
        s[t] += x;
        __syncthreads();
    }
    if (t < B) bbase[t] = s[t] - v;          // exclusive
    if (t == 0) offs[N] = E;
}

// ---------------------------------------------------------------------------
// K2c: add block bases; init cursor
// ---------------------------------------------------------------------------
__global__ __launch_bounds__(256) void k_scan_final(int* __restrict__ offs,
                                                    int* __restrict__ cursor,
                                                    const int* __restrict__ bbase,
                                                    int N) {
    int n = blockIdx.x * 256 + threadIdx.x;
    if (n < N) {
        int o = offs[n] + bbase[blockIdx.x];
        offs[n] = o;
        cursor[n] = o;
    }
}

// ---------------------------------------------------------------------------
// K3: place edges into CSR buckets: st[p] = (row, ew_bits)
// ---------------------------------------------------------------------------
__global__ __launch_bounds__(256) void k_place(const int* __restrict__ row,
                                               const int* __restrict__ col,
                                               const float* __restrict__ ew,
                                               int* __restrict__ cursor,
                                               int2* __restrict__ st, int E) {
    int e = blockIdx.x * 256 + threadIdx.x;
    if (e >= E) return;
    int c = col[e];
    int p = atomicAdd(&cursor[c], 1);
    st[p] = make_int2(row[e], __float_as_int(ew[e]));
}

// ---------------------------------------------------------------------------
// K4: weighted in-degree from buckets (no atomics), dinv = rsqrt(1 + sum ew)
// one wave per node
// ---------------------------------------------------------------------------
__global__ __launch_bounds__(256) void k_degsum(const int* __restrict__ offs,
                                                const int2* __restrict__ st,
                                                float* __restrict__ dinv, int N) {
    int tid = threadIdx.x;
    int lane = tid & 63;
    int w = tid >> 6;
    int n = blockIdx.x * 4 + w;
    if (n >= N) return;
    int beg = offs[n], end = offs[n + 1];
    float s = 0.0f;
    for (int e = beg + lane; e < end; e += 64) {
        s += __int_as_float(st[e].y);
    }
#pragma unroll
    for (int off = 1; off < 64; off <<= 1) s += __shfl_xor(s, off, 64);
    if (lane == 0) dinv[n] = rsqrtf(1.0f + s);
}

// ---------------------------------------------------------------------------
// K5: h1 = x @ W1  — thread per node, acc[16] in VGPRs, W via uniform (s_load)
// ---------------------------------------------------------------------------
__global__ __launch_bounds__(128) void k_gemm1(const float* __restrict__ x,
                                               const float* __restrict__ W,
                                               float* __restrict__ h, int N) {
    int n = blockIdx.x * 128 + threadIdx.x;
    if (n >= N) return;
    float acc[HID];
#pragma unroll
    for (int j = 0; j < HID; ++j) acc[j] = 0.0f;
    const float4* xr = (const float4*)(x + (size_t)n * F_IN);
#pragma unroll 4
    for (int k4 = 0; k4 < F_IN / 4; ++k4) {
        float4 xv = xr[k4];
        const float* wk = W + k4 * 4 * HID;   // wave-uniform address
#pragma unroll
        for (int j = 0; j < HID; ++j) acc[j] += xv.x * wk[j];
#pragma unroll
        for (int j = 0; j < HID; ++j) acc[j] += xv.y * wk[HID + j];
#pragma unroll
        for (int j = 0; j < HID; ++j) acc[j] += xv.z * wk[2 * HID + j];
#pragma unroll
        for (int j = 0; j < HID; ++j) acc[j] += xv.w * wk[3 * HID + j];
    }
    float4* hp = (float4*)(h + (size_t)n * HID);
    hp[0] = make_float4(acc[0], acc[1], acc[2], acc[3]);
    hp[1] = make_float4(acc[4], acc[5], acc[6], acc[7]);
    hp[2] = make_float4(acc[8], acc[9], acc[10], acc[11]);
    hp[3] = make_float4(acc[12], acc[13], acc[14], acc[15]);
}

// ---------------------------------------------------------------------------
// K6: gather-aggregate, one wave per node.
// lane = 4*i + q : edge slot i (0..15), dim-quad q (0..3).
// out[n] = sum_{e in bucket(n)} dinv[r]*ew*dinv[n] * src[r] + dinv[n]^2*src[n]
//          (+ bias, relu if RELU)
// ---------------------------------------------------------------------------
template <bool RELU>
__global__ __launch_bounds__(256) void k_agg(const int* __restrict__ offs,
                                             const int2* __restrict__ st,
                                             const float* __restrict__ dinv,
                                             const float* __restrict__ src,
                                             const float* __restrict__ bias,
                                             float* __restrict__ dst, int N) {
    int tid = threadIdx.x;
    int lane = tid & 63;
    int w = tid >> 6;
    int n = blockIdx.x * 4 + w;
    if (n >= N) return;
    int q = lane & 3;
    int i = lane >> 2;
    int beg = offs[n], end = offs[n + 1];
    float din = dinv[n];
    float4 acc = make_float4(0.f, 0.f, 0.f, 0.f);
    for (int e = beg + i; e < end; e += 16) {
        int2 t = st[e];
        float nrm = dinv[t.x] * __int_as_float(t.y) * din;
        float4 v = ((const float4*)(src + (size_t)t.x * HID))[q];
        acc.x += nrm * v.x;
        acc.y += nrm * v.y;
        acc.z += nrm * v.z;
        acc.w += nrm * v.w;
    }
#pragma unroll
    for (int off = 4; off < 64; off <<= 1) {
        acc.x += __shfl_xor(acc.x, off, 64);
        acc.y += __shfl_xor(acc.y, off, 64);
        acc.z += __shfl_xor(acc.z, off, 64);
        acc.w += __shfl_xor(acc.w, off, 64);
    }
    if (i == 0) {
        float d2 = din * din;
        float4 sv = ((const float4*)(src + (size_t)n * HID))[q];
        float4 r;
        r.x = acc.x + d2 * sv.x;
        r.y = acc.y + d2 * sv.y;
        r.z = acc.z + d2 * sv.z;
        r.w = acc.w + d2 * sv.w;
        if (RELU) {
            float4 bq = ((const float4*)bias)[q];
            r.x = fmaxf(r.x + bq.x, 0.f);
            r.y = fmaxf(r.y + bq.y, 0.f);
            r.z = fmaxf(r.z + bq.z, 0.f);
            r.w = fmaxf(r.w + bq.w, 0.f);
        }
        ((float4*)(dst + (size_t)n * HID))[q] = r;
    }
}

// ---------------------------------------------------------------------------
// K7: epilogue — logits = g@W2 + b2; log_softmax. One wave per node.
// ---------------------------------------------------------------------------
__global__ __launch_bounds__(256) void k_epilogue(const float* __restrict__ g,
                                                  const float* __restrict__ W2,
                                                  const float* __restrict__ b2,
                                                  float* __restrict__ out, int N) {
    __shared__ float Ws[HID * C_OUT];
    __shared__ float bs[C_OUT];
    int tid = threadIdx.x;
    for (int i = tid; i < HID * C_OUT; i += 256) Ws[i] = W2[i];
    if (tid < C_OUT) bs[tid] = b2[tid];
    __syncthreads();

    int lane = tid & 63;
    int w = tid >> 6;
    int n = blockIdx.x * 4 + w;
    if (n >= N) return;

    float logit = -INFINITY;
    if (lane < C_OUT) {
        float acc = bs[lane];
        const float* gr = g + (size_t)n * HID;
#pragma unroll
        for (int j = 0; j < HID; ++j) acc += gr[j] * Ws[j * C_OUT + lane];
        logit = acc;
    }
    float m = logit;
#pragma unroll
    for (int off = 32; off > 0; off >>= 1) m = fmaxf(m, __shfl_xor(m, off, 64));
    float ex = (lane < C_OUT) ? __expf(logit - m) : 0.0f;
    float s = ex;
#pragma unroll
    for (int off = 32; off > 0; off >>= 1) s += __shfl_xor(s, off, 64);
    if (lane < C_OUT) out[(size_t)n * C_OUT + lane] = logit - m - __logf(s);
}

// ---------------------------------------------------------------------------
extern "C" void kernel_launch(void* const* d_in, const int* in_sizes, int n_in,
                              void* d_out, int out_size, void* d_ws, size_t ws_size,
                              hipStream_t stream) {
    const float* x   = (const float*)d_in[0];
    const int*   ei  = (const int*)d_in[1];
    const float* ew  = (const float*)d_in[2];
    const float* W1  = (const float*)d_in[3];
    const float* b1  = (const float*)d_in[4];
    const float* W2  = (const float*)d_in[5];
    const float* b2  = (const float*)d_in[6];
    float* out = (float*)d_out;

    const int N = in_sizes[0] / F_IN;     // 100000
    const int E = in_sizes[2];            // 3200000
    const int* row = ei;
    const int* col = ei + E;

    // workspace carve (4-byte words)
    int* wsi = (int*)d_ws;
    size_t o = 0;
    int* cnt    = wsi + o; o += N;
    int* offs   = wsi + o; o += (size_t)N + 16;
    int* cursor = wsi + o; o += N;
    int* bsum   = wsi + o; o += 512;
    int* bbase  = wsi + o; o += 512;
    float* dinv = (float*)(wsi + o); o += N;
    float* h1   = (float*)(wsi + o); o += (size_t)N * HID;
    float* a1   = (float*)(wsi + o); o += (size_t)N * HID;
    float* g    = (float*)(wsi + o); o += (size_t)N * HID;
    int2* st    = (int2*)(wsi + o); o += (size_t)E * 2;

    int gN  = (N + 255) / 256;            // 391
    int gE  = (E + 255) / 256;            // 12500
    int gW  = (N + 3) / 4;                // 25000  (wave-per-node kernels)

    k_zero<<<gN, 256, 0, stream>>>(cnt, N);
    k_hist<<<gE, 256, 0, stream>>>(col, cnt, E);
    k_scan_block<<<gN, 256, 0, stream>>>(cnt, offs, bsum, N);
    k_scan_top<<<1, 512, 0, stream>>>(bsum, bbase, offs, gN, N, E);
    k_scan_final<<<gN, 256, 0, stream>>>(offs, cursor, bbase, N);
    k_place<<<gE, 256, 0, stream>>>(row, col, ew, cursor, st, E);
    k_degsum<<<gW, 256, 0, stream>>>(offs, st, dinv, N);
    k_gemm1<<<(N + 127) / 128, 128, 0, stream>>>(x, W1, h1, N);
    k_agg<true><<<gW, 256, 0, stream>>>(offs, st, dinv, h1, b1, a1, N);
    k_agg<false><<<gW, 256, 0, stream>>>(offs, st, dinv, a1, nullptr, g, N);
    k_epilogue<<<gW, 256, 0, stream>>>(g, W2, b2, out, N);
}